// Round 5
// baseline (237.383 us; speedup 1.0000x reference)
//
#include <hip/hip_runtime.h>
#include <hip/hip_bf16.h>

#define SQ 2048
#define SK 2048
#define DD 128
#define NBH 32
#define QBLK 128
#define KBLK 32
#define NKT (SK / KBLK)
#define SCALE 0.20884964425119185f
#define SCL2 (SCALE * 1.4426950408889634f)   // fold log2(e): exp2

typedef __attribute__((ext_vector_type(8))) short short8;
typedef __attribute__((ext_vector_type(4))) float f32x4;

// LDS arena (34816 B):
//  prologue: Q bf16 [128][272B] = 34816 (whole arena), hoisted to regs
//  main loop: K bf16 [32][272B] at 0 (8704) ; Vt bf16 [128] rows pitch 84B at 8704 (10752)
#define KPITCH 272
#define VPITCH 84
#define VOFF 8704
#define SMEM_BYTES 34816

static __device__ __forceinline__ unsigned int pk_bf16(float lo, float hi) {
    float2 f2; f2.x = lo; f2.y = hi;
    __hip_bfloat162 h = __float22bfloat162_rn(f2);   // v_cvt_pk_bf16_f32
    union { __hip_bfloat162 h2; unsigned int u; } cv; cv.h2 = h;
    return cv.u;
}

// softmax + bf16 pack + shfl-redistribute into PV A-operand layout (k = 8g+j)
// (verbatim R3-verified)
#define SOFTMAX_PACK(PA, SA_, SB_, MCa, MCb, LPART)                            \
  { float p_[8];                                                               \
    p_[0] = __builtin_amdgcn_exp2f(SA_[0]*SCL2);                               \
    p_[1] = __builtin_amdgcn_exp2f(SA_[1]*SCL2);                               \
    p_[2] = __builtin_amdgcn_exp2f(SA_[2]*SCL2);                               \
    p_[3] = __builtin_amdgcn_exp2f(SA_[3]*SCL2);                               \
    p_[4] = __builtin_amdgcn_exp2f(SB_[0]*SCL2);                               \
    p_[5] = __builtin_amdgcn_exp2f(SB_[1]*SCL2);                               \
    p_[6] = __builtin_amdgcn_exp2f(SB_[2]*SCL2);                               \
    p_[7] = __builtin_amdgcn_exp2f(SB_[3]*SCL2);                               \
    LPART += ((p_[0]+p_[1]) + (p_[2]+p_[3])) + ((p_[4]+p_[5]) + (p_[6]+p_[7]));\
    p_[0]*=MCa.x; p_[1]*=MCa.y; p_[2]*=MCa.z; p_[3]*=MCa.w;                    \
    p_[4]*=MCb.x; p_[5]*=MCb.y; p_[6]*=MCb.z; p_[7]*=MCb.w;                    \
    unsigned int P0 = pk_bf16(p_[0],p_[1]), P1 = pk_bf16(p_[2],p_[3]);         \
    unsigned int P2 = pk_bf16(p_[4],p_[5]), P3 = pk_bf16(p_[6],p_[7]);         \
    unsigned int a0 = __shfl((int)P0, sA), a2 = __shfl((int)P2, sA);           \
    unsigned int b0 = __shfl((int)P1, sA), b2 = __shfl((int)P3, sA);           \
    unsigned int c0 = __shfl((int)P0, sB), c2 = __shfl((int)P2, sB);           \
    unsigned int d0 = __shfl((int)P1, sB), d2 = __shfl((int)P3, sB);           \
    union { unsigned int u[4]; short8 v; } pb_;                                \
    pb_.u[0] = hi ? a2 : a0; pb_.u[1] = hi ? b2 : b0;                          \
    pb_.u[2] = hi ? c2 : c0; pb_.u[3] = hi ? d2 : d0;                          \
    PA = pb_.v; }

// one K-tile: prefetch next (regs) | stage current | barrier | QK | softmax | PV | barrier
#define BODY(XC, MC, XN, MN, KT)                                               \
  {                                                                            \
    const int kb  = (KT) * KBLK;                                               \
    const int kbn = ((KT) < NKT - 1) ? kb + KBLK : kb;                         \
    _Pragma("unroll")                                                          \
    for (int b = 0; b < 4; ++b) {     /* prefetch next x2: 2x2 blocks */       \
        const float* r0 = x2b + (size_t)(kbn + kqb + 8*b) * DD + 2*d2;         \
        XN[2*b]   = *(const float2*)(r0);                                      \
        XN[2*b+1] = *(const float2*)(r0 + DD);                                 \
    }                                                                          \
    MN[0] = *(const float4*)(mq0 + kbn);                                       \
    MN[1] = *(const float4*)(mq0 + kbn + 16);                                  \
    MN[2] = *(const float4*)(mq1 + kbn);                                       \
    MN[3] = *(const float4*)(mq1 + kbn + 16);                                  \
    _Pragma("unroll")                                                          \
    for (int b = 0; b < 4; ++b) {     /* stage current: K rows + Vt cols */    \
        const int k = kqb + 8*b;                                               \
        float2 lo = XC[2*b], hi2 = XC[2*b+1];                                  \
        *(unsigned int*)(smem + (k)   * KPITCH + 4*d2) = pk_bf16(lo.x, lo.y);  \
        *(unsigned int*)(smem + (k+1) * KPITCH + 4*d2) = pk_bf16(hi2.x, hi2.y);\
        *(unsigned int*)(smem + VOFF + (2*d2)   * VPITCH + 2*k) =              \
            pk_bf16(lo.x, hi2.x);                                              \
        *(unsigned int*)(smem + VOFF + (2*d2+1) * VPITCH + 2*k) =              \
            pk_bf16(lo.y, hi2.y);                                              \
    }                                                                          \
    asm volatile("s_waitcnt lgkmcnt(0)" ::: "memory");                         \
    __builtin_amdgcn_sched_barrier(0);                                         \
    __builtin_amdgcn_s_barrier();          /* raw: vmcnt stays in flight */    \
    __builtin_amdgcn_sched_barrier(0);                                         \
    f32x4 s00={0,0,0,0}, s01={0,0,0,0}, s10={0,0,0,0}, s11={0,0,0,0};          \
    __builtin_amdgcn_s_setprio(1);                                             \
    _Pragma("unroll")                                                          \
    for (int ks = 0; ks < 4; ++ks) {                                           \
      short8 ka0 = *(const short8*)(smem + (c)      * KPITCH + ks*64 + 16*g);  \
      short8 ka1 = *(const short8*)(smem + (16 + c) * KPITCH + ks*64 + 16*g);  \
      s00 = __builtin_amdgcn_mfma_f32_16x16x32_bf16(ka0, qf0[ks], s00, 0,0,0); \
      s01 = __builtin_amdgcn_mfma_f32_16x16x32_bf16(ka1, qf0[ks], s01, 0,0,0); \
      s10 = __builtin_amdgcn_mfma_f32_16x16x32_bf16(ka0, qf1[ks], s10, 0,0,0); \
      s11 = __builtin_amdgcn_mfma_f32_16x16x32_bf16(ka1, qf1[ks], s11, 0,0,0); \
    }                                                                          \
    __builtin_amdgcn_s_setprio(0);                                             \
    short8 pa0, pa1;                                                           \
    SOFTMAX_PACK(pa0, s00, s01, MC[0], MC[1], l0p)                             \
    SOFTMAX_PACK(pa1, s10, s11, MC[2], MC[3], l1p)                             \
    __builtin_amdgcn_s_setprio(1);                                             \
    _Pragma("unroll")                                                          \
    for (int d8 = 0; d8 < 8; ++d8) {                                           \
      const unsigned char* vr = smem + VOFF + (d8*16 + c) * VPITCH + 16*g;     \
      union { unsigned int u[4]; short8 s; } vv;                               \
      vv.u[0] = *(const unsigned int*)(vr);                                    \
      vv.u[1] = *(const unsigned int*)(vr + 4);                                \
      vv.u[2] = *(const unsigned int*)(vr + 8);                                \
      vv.u[3] = *(const unsigned int*)(vr + 12);                               \
      o0[d8] = __builtin_amdgcn_mfma_f32_16x16x32_bf16(pa0, vv.s, o0[d8], 0,0,0); \
      o1[d8] = __builtin_amdgcn_mfma_f32_16x16x32_bf16(pa1, vv.s, o1[d8], 0,0,0); \
    }                                                                          \
    __builtin_amdgcn_s_setprio(0);                                             \
    asm volatile("s_waitcnt lgkmcnt(0)" ::: "memory");                         \
    __builtin_amdgcn_sched_barrier(0);                                         \
    __builtin_amdgcn_s_barrier();          /* reads done before next staging */\
    __builtin_amdgcn_sched_barrier(0);                                         \
  }

__global__ __launch_bounds__(256, 2) void fattn(
    const float* __restrict__ x1, const float* __restrict__ x2,
    const float* __restrict__ mask, float* __restrict__ out)
{
    __shared__ __align__(16) unsigned char smem[SMEM_BYTES];
    const int tid  = threadIdx.x;
    const int lane = tid & 63, wid = tid >> 6;
    const int c = lane & 15, g = lane >> 4;

    // XCD-aware bijective swizzle: 512 blocks = 64 per XCD, contiguous chunk
    const int bid = blockIdx.x;
    const int swz = (bid & 7) * 64 + (bid >> 3);
    const int bh = swz >> 4;             // SQ/QBLK = 16 q-tiles per (b,h)
    const int qb = swz & 15;

    const float* x1b = x1 + ((size_t)bh * SQ + (size_t)qb * QBLK) * DD;
    const float* x2b = x2 + (size_t)bh * SK * DD;
    const float* mb  = mask + ((size_t)bh * SQ + (size_t)qb * QBLK) * SK;
    float*      outb = out + ((size_t)bh * SQ + (size_t)qb * QBLK) * DD;

    // shfl sources for P redistribution (R1/R3-verified)
    const int sA = c + ((g & 1) << 5);
    const int sB = sA + 16;
    const bool hi = (g >= 2);

    // staging mapping: thread owns 2x2 (k,d) blocks: d = 2*d2, k = kqb + 8b (+1)
    const int d2  = tid & 63;
    const int kqb = (tid >> 6) * 2;

    // mask rows (q-local = wid*16 + c), cols kb + 4g (+16); subtile 2 at +64 rows
    const float* mq0 = mb + (size_t)(wid*16 + c) * SK + 4*g;
    const float* mq1 = mq0 + (size_t)64 * SK;

    // ---- prologue: tile-0 x2 + mask loads (fly under Q staging) ----
    float2 xA[8], xB[8];
    float4 mA[4], mB[4];
#pragma unroll
    for (int b = 0; b < 4; ++b) {
        const float* r0 = x2b + (size_t)(kqb + 8*b) * DD + 2*d2;
        xA[2*b]   = *(const float2*)(r0);
        xA[2*b+1] = *(const float2*)(r0 + DD);
    }
    mA[0] = *(const float4*)(mq0);      mA[1] = *(const float4*)(mq0 + 16);
    mA[2] = *(const float4*)(mq1);      mA[3] = *(const float4*)(mq1 + 16);

    // ---- stage Q: fp32 -> bf16, [128][272B] ----
#pragma unroll
    for (int i = 0; i < 16; ++i) {
        int f = tid + 256 * i;
        int row = f >> 5, c4 = (f & 31) * 4;
        float4 v = *(const float4*)(x1b + row * DD + c4);
        unsigned long long w = (unsigned long long)pk_bf16(v.x, v.y)
                             | ((unsigned long long)pk_bf16(v.z, v.w) << 32);
        *(unsigned long long*)(smem + row * 272 + c4 * 2) = w;
    }
    __syncthreads();

    // hoist Q fragments: 2 q-subtiles x 4 ks (B-operand: q = c, d = 32ks+8g+j)
    short8 qf0[4], qf1[4];
#pragma unroll
    for (int ks = 0; ks < 4; ++ks) {
        qf0[ks] = *(const short8*)(smem + (wid*16 + c) * 272 + ks*64 + 16*g);
        qf1[ks] = *(const short8*)(smem + (64 + wid*16 + c) * 272 + ks*64 + 16*g);
    }
    __syncthreads();   // Q reads done; K/Vt staging may overwrite arena

    f32x4 o0[8] = {}, o1[8] = {};   // O[q][d]: lane holds O[4g+r][d8*16+c]
    float l0p = 0.f, l1p = 0.f;

    for (int kt2 = 0; kt2 < NKT / 2; ++kt2) {
        BODY(xA, mA, xB, mB, 2*kt2)
        BODY(xB, mB, xA, mA, 2*kt2 + 1)
    }

    // ---- epilogue: reduce l across g, per-row denominators via shfl, store ----
    float l0 = l0p; l0 += __shfl_xor(l0, 16); l0 += __shfl_xor(l0, 32);
    float l1 = l1p; l1 += __shfl_xor(l1, 16); l1 += __shfl_xor(l1, 32);
    float il00 = 1.0f / __shfl(l0, 4*g + 0), il01 = 1.0f / __shfl(l0, 4*g + 1);
    float il02 = 1.0f / __shfl(l0, 4*g + 2), il03 = 1.0f / __shfl(l0, 4*g + 3);
    float il10 = 1.0f / __shfl(l1, 4*g + 0), il11 = 1.0f / __shfl(l1, 4*g + 1);
    float il12 = 1.0f / __shfl(l1, 4*g + 2), il13 = 1.0f / __shfl(l1, 4*g + 3);

    float* orow0 = outb + (size_t)(wid*16) * DD;
    float* orow1 = outb + (size_t)(64 + wid*16) * DD;
#pragma unroll
    for (int d8 = 0; d8 < 8; ++d8) {
        orow0[(4*g + 0) * DD + d8*16 + c] = o0[d8][0] * il00;
        orow0[(4*g + 1) * DD + d8*16 + c] = o0[d8][1] * il01;
        orow0[(4*g + 2) * DD + d8*16 + c] = o0[d8][2] * il02;
        orow0[(4*g + 3) * DD + d8*16 + c] = o0[d8][3] * il03;
        orow1[(4*g + 0) * DD + d8*16 + c] = o1[d8][0] * il10;
        orow1[(4*g + 1) * DD + d8*16 + c] = o1[d8][1] * il11;
        orow1[(4*g + 2) * DD + d8*16 + c] = o1[d8][2] * il12;
        orow1[(4*g + 3) * DD + d8*16 + c] = o1[d8][3] * il13;
    }
}

extern "C" void kernel_launch(void* const* d_in, const int* in_sizes, int n_in,
                              void* d_out, int out_size, void* d_ws, size_t ws_size,
                              hipStream_t stream) {
    const float* x1   = (const float*)d_in[0];
    const float* x2   = (const float*)d_in[1];
    const float* mask = (const float*)d_in[2];
    fattn<<<dim3(NBH * (SQ / QBLK)), dim3(256), 0, stream>>>(x1, x2, mask, (float*)d_out);
}

// Round 6
// 206.008 us; speedup vs baseline: 1.1523x; 1.1523x over previous
//
#include <hip/hip_runtime.h>
#include <hip/hip_bf16.h>

#define SQ 2048
#define SK 2048
#define DD 128
#define NBH 32
#define QBLK 128
#define KBLK 32
#define NKT (SK / KBLK)
#define SCALE 0.20884964425119185f
#define SCL2 (SCALE * 1.4426950408889634f)   // fold log2(e): exp2

typedef __attribute__((ext_vector_type(8))) short short8;
typedef __attribute__((ext_vector_type(4))) float f32x4;

// LDS: K bf16 [32][272B] at 0 (8704); Vt bf16 [128] rows pitch 80B at 8704 (10240)
#define KPITCH 272
#define VPITCH 80
#define VOFF 8704
#define SMEM_BYTES 18944

static __device__ __forceinline__ unsigned int pk_bf16(float lo, float hi) {
    float2 f2; f2.x = lo; f2.y = hi;
    __hip_bfloat162 h = __float22bfloat162_rn(f2);   // v_cvt_pk_bf16_f32
    union { __hip_bfloat162 h2; unsigned int u; } cv; cv.h2 = h;
    return cv.u;
}

// softmax + bf16 pack + shfl-redistribute into PV A-operand layout (R3/R5-proven)
#define SOFTMAX_PACK(PA, SA_, SB_, MCa, MCb, LPART)                            \
  { float p_[8];                                                               \
    p_[0] = __builtin_amdgcn_exp2f(SA_[0]*SCL2);                               \
    p_[1] = __builtin_amdgcn_exp2f(SA_[1]*SCL2);                               \
    p_[2] = __builtin_amdgcn_exp2f(SA_[2]*SCL2);                               \
    p_[3] = __builtin_amdgcn_exp2f(SA_[3]*SCL2);                               \
    p_[4] = __builtin_amdgcn_exp2f(SB_[0]*SCL2);                               \
    p_[5] = __builtin_amdgcn_exp2f(SB_[1]*SCL2);                               \
    p_[6] = __builtin_amdgcn_exp2f(SB_[2]*SCL2);                               \
    p_[7] = __builtin_amdgcn_exp2f(SB_[3]*SCL2);                               \
    LPART += ((p_[0]+p_[1]) + (p_[2]+p_[3])) + ((p_[4]+p_[5]) + (p_[6]+p_[7]));\
    p_[0]*=MCa.x; p_[1]*=MCa.y; p_[2]*=MCa.z; p_[3]*=MCa.w;                    \
    p_[4]*=MCb.x; p_[5]*=MCb.y; p_[6]*=MCb.z; p_[7]*=MCb.w;                    \
    unsigned int P0 = pk_bf16(p_[0],p_[1]), P1 = pk_bf16(p_[2],p_[3]);         \
    unsigned int P2 = pk_bf16(p_[4],p_[5]), P3 = pk_bf16(p_[6],p_[7]);         \
    unsigned int a0 = __shfl((int)P0, sA), a2 = __shfl((int)P2, sA);           \
    unsigned int b0 = __shfl((int)P1, sA), b2 = __shfl((int)P3, sA);           \
    unsigned int c0 = __shfl((int)P0, sB), c2 = __shfl((int)P2, sB);           \
    unsigned int d0 = __shfl((int)P1, sB), d2 = __shfl((int)P3, sB);           \
    union { unsigned int u[4]; short8 v; } pb_;                                \
    pb_.u[0] = hi ? a2 : a0; pb_.u[1] = hi ? b2 : b0;                          \
    pb_.u[2] = hi ? c2 : c0; pb_.u[3] = hi ? d2 : d0;                          \
    PA = pb_.v; }

#define SYNC_STAGE()                                                           \
    asm volatile("s_waitcnt lgkmcnt(0)" ::: "memory");                         \
    __builtin_amdgcn_sched_barrier(0);                                         \
    __builtin_amdgcn_s_barrier();                                              \
    __builtin_amdgcn_sched_barrier(0);

#define COMPUTE_TILE(MC0, MC1, MC2, MC3)                                       \
    f32x4 s00={0,0,0,0}, s01={0,0,0,0}, s10={0,0,0,0}, s11={0,0,0,0};          \
    __builtin_amdgcn_s_setprio(1);                                             \
    _Pragma("unroll")                                                          \
    for (int ks = 0; ks < 4; ++ks) {                                           \
      short8 ka0 = *(const short8*)(smem + (c)      * KPITCH + ks*64 + 16*g);  \
      short8 ka1 = *(const short8*)(smem + (16 + c) * KPITCH + ks*64 + 16*g);  \
      s00 = __builtin_amdgcn_mfma_f32_16x16x32_bf16(ka0, qf0[ks], s00, 0,0,0); \
      s01 = __builtin_amdgcn_mfma_f32_16x16x32_bf16(ka1, qf0[ks], s01, 0,0,0); \
      s10 = __builtin_amdgcn_mfma_f32_16x16x32_bf16(ka0, qf1[ks], s10, 0,0,0); \
      s11 = __builtin_amdgcn_mfma_f32_16x16x32_bf16(ka1, qf1[ks], s11, 0,0,0); \
    }                                                                          \
    __builtin_amdgcn_s_setprio(0);                                             \
    short8 pa0, pa1;                                                           \
    SOFTMAX_PACK(pa0, s00, s01, MC0, MC1, l0p)                                 \
    SOFTMAX_PACK(pa1, s10, s11, MC2, MC3, l1p)                                 \
    __builtin_amdgcn_s_setprio(1);                                             \
    _Pragma("unroll")                                                          \
    for (int d8 = 0; d8 < 8; ++d8) {                                           \
      short8 vv = *(const short8*)(smem + VOFF + (d8*16 + c)*VPITCH + 16*g);   \
      o0[d8] = __builtin_amdgcn_mfma_f32_16x16x32_bf16(pa0, vv, o0[d8], 0,0,0);\
      o1[d8] = __builtin_amdgcn_mfma_f32_16x16x32_bf16(pa1, vv, o1[d8], 0,0,0);\
    }                                                                          \
    __builtin_amdgcn_s_setprio(0);                                             \
    SYNC_STAGE()

// ------- bf16-source body -------
#define BODY_BF(KC0, KC1, VC0, VC1, MC0, MC1, MC2, MC3,                        \
                KN0, KN1, VN0, VN1, MN0, MN1, MN2, MN3, KT)                    \
  { const int kbn = ((KT) < NKT - 1) ? ((KT) + 1) * KBLK : (KT) * KBLK;        \
    KN0 = *(const short8*)(x2bb + (size_t)(kbn + kk)      * DD + kd0);         \
    KN1 = *(const short8*)(x2bb + (size_t)(kbn + kk + 16) * DD + kd0);         \
    VN0 = *(const short8*)(x2bb + (size_t)(kbn + vk) * DD + vd0);              \
    VN1 = *(const short8*)(x2bb + (size_t)(kbn + vk) * DD + vd0 + 64);         \
    MN0 = *(const float4*)(mq0 + kbn);                                         \
    MN1 = *(const float4*)(mq0 + kbn + 16);                                    \
    MN2 = *(const float4*)(mq1 + kbn);                                         \
    MN3 = *(const float4*)(mq1 + kbn + 16);                                    \
    *(short8*)(smem + (kk)      * KPITCH + 2*kd0) = KC0;                       \
    *(short8*)(smem + (kk + 16) * KPITCH + 2*kd0) = KC1;                       \
    { union { short8 s; unsigned short u[8]; } va_, vb_;                       \
      va_.s = VC0; vb_.s = VC1;                                                \
      _Pragma("unroll")                                                        \
      for (int j = 0; j < 8; ++j) {                                            \
        *(unsigned short*)(smem + VOFF + (vd0 + j)      * VPITCH + 2*vk) = va_.u[j]; \
        *(unsigned short*)(smem + VOFF + (vd0 + 64 + j) * VPITCH + 2*vk) = vb_.u[j]; \
      } }                                                                      \
    SYNC_STAGE()                                                               \
    COMPUTE_TILE(MC0, MC1, MC2, MC3)                                           \
  }

// ------- fp32-source body (fallback when ws too small) -------
#define BODY_F32(KC0a,KC0b,KC1a,KC1b, VC0a,VC0b,VC1a,VC1b, MC0,MC1,MC2,MC3,    \
                 KN0a,KN0b,KN1a,KN1b, VN0a,VN0b,VN1a,VN1b, MN0,MN1,MN2,MN3, KT)\
  { const int kbn = ((KT) < NKT - 1) ? ((KT) + 1) * KBLK : (KT) * KBLK;        \
    KN0a = *(const float4*)(x2fb + (size_t)(kbn + kk)      * DD + kd0);        \
    KN0b = *(const float4*)(x2fb + (size_t)(kbn + kk)      * DD + kd0 + 4);    \
    KN1a = *(const float4*)(x2fb + (size_t)(kbn + kk + 16) * DD + kd0);        \
    KN1b = *(const float4*)(x2fb + (size_t)(kbn + kk + 16) * DD + kd0 + 4);    \
    VN0a = *(const float4*)(x2fb + (size_t)(kbn + vk) * DD + vd0);             \
    VN0b = *(const float4*)(x2fb + (size_t)(kbn + vk) * DD + vd0 + 4);         \
    VN1a = *(const float4*)(x2fb + (size_t)(kbn + vk) * DD + vd0 + 64);        \
    VN1b = *(const float4*)(x2fb + (size_t)(kbn + vk) * DD + vd0 + 68);        \
    MN0 = *(const float4*)(mq0 + kbn);                                         \
    MN1 = *(const float4*)(mq0 + kbn + 16);                                    \
    MN2 = *(const float4*)(mq1 + kbn);                                         \
    MN3 = *(const float4*)(mq1 + kbn + 16);                                    \
    { union { unsigned int u[4]; short8 s; } k0_, k1_;                         \
      k0_.u[0]=pk_bf16(KC0a.x,KC0a.y); k0_.u[1]=pk_bf16(KC0a.z,KC0a.w);        \
      k0_.u[2]=pk_bf16(KC0b.x,KC0b.y); k0_.u[3]=pk_bf16(KC0b.z,KC0b.w);        \
      k1_.u[0]=pk_bf16(KC1a.x,KC1a.y); k1_.u[1]=pk_bf16(KC1a.z,KC1a.w);        \
      k1_.u[2]=pk_bf16(KC1b.x,KC1b.y); k1_.u[3]=pk_bf16(KC1b.z,KC1b.w);        \
      *(short8*)(smem + (kk)      * KPITCH + 2*kd0) = k0_.s;                   \
      *(short8*)(smem + (kk + 16) * KPITCH + 2*kd0) = k1_.s; }                 \
    { unsigned int w;                                                          \
      w = pk_bf16(VC0a.x, VC0a.y);                                             \
      *(unsigned short*)(smem + VOFF + (vd0+0)*VPITCH + 2*vk) = (unsigned short)w;       \
      *(unsigned short*)(smem + VOFF + (vd0+1)*VPITCH + 2*vk) = (unsigned short)(w>>16); \
      w = pk_bf16(VC0a.z, VC0a.w);                                             \
      *(unsigned short*)(smem + VOFF + (vd0+2)*VPITCH + 2*vk) = (unsigned short)w;       \
      *(unsigned short*)(smem + VOFF + (vd0+3)*VPITCH + 2*vk) = (unsigned short)(w>>16); \
      w = pk_bf16(VC0b.x, VC0b.y);                                             \
      *(unsigned short*)(smem + VOFF + (vd0+4)*VPITCH + 2*vk) = (unsigned short)w;       \
      *(unsigned short*)(smem + VOFF + (vd0+5)*VPITCH + 2*vk) = (unsigned short)(w>>16); \
      w = pk_bf16(VC0b.z, VC0b.w);                                             \
      *(unsigned short*)(smem + VOFF + (vd0+6)*VPITCH + 2*vk) = (unsigned short)w;       \
      *(unsigned short*)(smem + VOFF + (vd0+7)*VPITCH + 2*vk) = (unsigned short)(w>>16); \
      w = pk_bf16(VC1a.x, VC1a.y);                                             \
      *(unsigned short*)(smem + VOFF + (vd0+64)*VPITCH + 2*vk) = (unsigned short)w;      \
      *(unsigned short*)(smem + VOFF + (vd0+65)*VPITCH + 2*vk) = (unsigned short)(w>>16);\
      w = pk_bf16(VC1a.z, VC1a.w);                                             \
      *(unsigned short*)(smem + VOFF + (vd0+66)*VPITCH + 2*vk) = (unsigned short)w;      \
      *(unsigned short*)(smem + VOFF + (vd0+67)*VPITCH + 2*vk) = (unsigned short)(w>>16);\
      w = pk_bf16(VC1b.x, VC1b.y);                                             \
      *(unsigned short*)(smem + VOFF + (vd0+68)*VPITCH + 2*vk) = (unsigned short)w;      \
      *(unsigned short*)(smem + VOFF + (vd0+69)*VPITCH + 2*vk) = (unsigned short)(w>>16);\
      w = pk_bf16(VC1b.z, VC1b.w);                                             \
      *(unsigned short*)(smem + VOFF + (vd0+70)*VPITCH + 2*vk) = (unsigned short)w;      \
      *(unsigned short*)(smem + VOFF + (vd0+71)*VPITCH + 2*vk) = (unsigned short)(w>>16);\
    }                                                                          \
    SYNC_STAGE()                                                               \
    COMPUTE_TILE(MC0, MC1, MC2, MC3)                                           \
  }

#define KERNEL_PRE()                                                           \
    __shared__ __align__(16) unsigned char smem[SMEM_BYTES];                   \
    const int tid  = threadIdx.x;                                              \
    const int lane = tid & 63, wid = tid >> 6;                                 \
    const int c = lane & 15, g = lane >> 4;                                    \
    const int bid = blockIdx.x;                                                \
    const int swz = (bid & 7) * 64 + (bid >> 3);   /* 512 = 64 x 8, bijective */\
    const int bh = swz >> 4;                                                   \
    const int qb = swz & 15;                                                   \
    const float* x1b = x1 + ((size_t)bh * SQ + (size_t)qb * QBLK) * DD;        \
    const float* mb  = mask + ((size_t)bh * SQ + (size_t)qb * QBLK) * SK;      \
    float*      outb = out + ((size_t)bh * SQ + (size_t)qb * QBLK) * DD;       \
    const int sA = c + ((g & 1) << 5);                                         \
    const int sB = sA + 16;                                                    \
    const bool hi = (g >= 2);                                                  \
    const int kk  = tid >> 4, kd0 = (tid & 15) * 8;                            \
    const int vk  = tid & 31, vd0 = (tid >> 5) * 8;                            \
    const float* mq0 = mb + (size_t)(wid*16 + c) * SK + 4*g;                   \
    const float* mq1 = mq0 + (size_t)64 * SK;

#define KERNEL_QLOAD()                                                         \
    short8 qf0[4], qf1[4];                                                     \
    {  const float* q0r = x1b + (size_t)(wid*16 + c) * DD;                     \
       const float* q1r = q0r + (size_t)64 * DD;                               \
       _Pragma("unroll")                                                       \
       for (int ks = 0; ks < 4; ++ks) {                                        \
           float4 a = *(const float4*)(q0r + ks*32 + 8*g);                     \
           float4 b = *(const float4*)(q0r + ks*32 + 8*g + 4);                 \
           union { unsigned int u[4]; short8 s; } t;                           \
           t.u[0]=pk_bf16(a.x,a.y); t.u[1]=pk_bf16(a.z,a.w);                   \
           t.u[2]=pk_bf16(b.x,b.y); t.u[3]=pk_bf16(b.z,b.w);                   \
           qf0[ks]=t.s;                                                        \
           a = *(const float4*)(q1r + ks*32 + 8*g);                            \
           b = *(const float4*)(q1r + ks*32 + 8*g + 4);                        \
           t.u[0]=pk_bf16(a.x,a.y); t.u[1]=pk_bf16(a.z,a.w);                   \
           t.u[2]=pk_bf16(b.x,b.y); t.u[3]=pk_bf16(b.z,b.w);                   \
           qf1[ks]=t.s;                                                        \
       } }

#define KERNEL_EPILOGUE()                                                      \
    float l0 = l0p; l0 += __shfl_xor(l0, 16); l0 += __shfl_xor(l0, 32);        \
    float l1 = l1p; l1 += __shfl_xor(l1, 16); l1 += __shfl_xor(l1, 32);        \
    float il00 = 1.0f/__shfl(l0, 4*g+0), il01 = 1.0f/__shfl(l0, 4*g+1);        \
    float il02 = 1.0f/__shfl(l0, 4*g+2), il03 = 1.0f/__shfl(l0, 4*g+3);        \
    float il10 = 1.0f/__shfl(l1, 4*g+0), il11 = 1.0f/__shfl(l1, 4*g+1);        \
    float il12 = 1.0f/__shfl(l1, 4*g+2), il13 = 1.0f/__shfl(l1, 4*g+3);        \
    float* orow0 = outb + (size_t)(wid*16) * DD;                               \
    float* orow1 = outb + (size_t)(64 + wid*16) * DD;                          \
    _Pragma("unroll")                                                          \
    for (int d8 = 0; d8 < 8; ++d8) {                                           \
        orow0[(4*g + 0) * DD + d8*16 + c] = o0[d8][0] * il00;                  \
        orow0[(4*g + 1) * DD + d8*16 + c] = o0[d8][1] * il01;                  \
        orow0[(4*g + 2) * DD + d8*16 + c] = o0[d8][2] * il02;                  \
        orow0[(4*g + 3) * DD + d8*16 + c] = o0[d8][3] * il03;                  \
        orow1[(4*g + 0) * DD + d8*16 + c] = o1[d8][0] * il10;                  \
        orow1[(4*g + 1) * DD + d8*16 + c] = o1[d8][1] * il11;                  \
        orow1[(4*g + 2) * DD + d8*16 + c] = o1[d8][2] * il12;                  \
        orow1[(4*g + 3) * DD + d8*16 + c] = o1[d8][3] * il13;                  \
    }

__global__ __launch_bounds__(256) void cvt_x2(const float* __restrict__ src,
                                              unsigned short* __restrict__ dst,
                                              int n4) {
    int i = blockIdx.x * 256 + threadIdx.x;
    const int stride = gridDim.x * 256;
    for (; i < n4; i += stride) {
        float4 v = ((const float4*)src)[i];
        uint2 w; w.x = pk_bf16(v.x, v.y); w.y = pk_bf16(v.z, v.w);
        ((uint2*)dst)[i] = w;
    }
}

__global__ __launch_bounds__(256, 2) void fattn_bf16(
    const float* __restrict__ x1, const unsigned short* __restrict__ x2b,
    const float* __restrict__ mask, float* __restrict__ out)
{
    KERNEL_PRE()
    const unsigned short* x2bb = x2b + (size_t)bh * SK * DD;

    // tile-0 prefetch (flies under Q load)
    short8 kA0 = *(const short8*)(x2bb + (size_t)(kk)      * DD + kd0);
    short8 kA1 = *(const short8*)(x2bb + (size_t)(kk + 16) * DD + kd0);
    short8 vA0 = *(const short8*)(x2bb + (size_t)(vk) * DD + vd0);
    short8 vA1 = *(const short8*)(x2bb + (size_t)(vk) * DD + vd0 + 64);
    float4 mA0 = *(const float4*)(mq0);
    float4 mA1 = *(const float4*)(mq0 + 16);
    float4 mA2 = *(const float4*)(mq1);
    float4 mA3 = *(const float4*)(mq1 + 16);
    short8 kB0, kB1, vB0, vB1; float4 mB0, mB1, mB2, mB3;

    KERNEL_QLOAD()

    f32x4 o0[8] = {}, o1[8] = {};
    float l0p = 0.f, l1p = 0.f;

    for (int kt2 = 0; kt2 < NKT / 2; ++kt2) {
        BODY_BF(kA0,kA1,vA0,vA1, mA0,mA1,mA2,mA3,
                kB0,kB1,vB0,vB1, mB0,mB1,mB2,mB3, 2*kt2)
        BODY_BF(kB0,kB1,vB0,vB1, mB0,mB1,mB2,mB3,
                kA0,kA1,vA0,vA1, mA0,mA1,mA2,mA3, 2*kt2 + 1)
    }
    KERNEL_EPILOGUE()
}

__global__ __launch_bounds__(256, 2) void fattn_f32(
    const float* __restrict__ x1, const float* __restrict__ x2,
    const float* __restrict__ mask, float* __restrict__ out)
{
    KERNEL_PRE()
    const float* x2fb = x2 + (size_t)bh * SK * DD;

    float4 kA0a = *(const float4*)(x2fb + (size_t)(kk)      * DD + kd0);
    float4 kA0b = *(const float4*)(x2fb + (size_t)(kk)      * DD + kd0 + 4);
    float4 kA1a = *(const float4*)(x2fb + (size_t)(kk + 16) * DD + kd0);
    float4 kA1b = *(const float4*)(x2fb + (size_t)(kk + 16) * DD + kd0 + 4);
    float4 vA0a = *(const float4*)(x2fb + (size_t)(vk) * DD + vd0);
    float4 vA0b = *(const float4*)(x2fb + (size_t)(vk) * DD + vd0 + 4);
    float4 vA1a = *(const float4*)(x2fb + (size_t)(vk) * DD + vd0 + 64);
    float4 vA1b = *(const float4*)(x2fb + (size_t)(vk) * DD + vd0 + 68);
    float4 mA0 = *(const float4*)(mq0);
    float4 mA1 = *(const float4*)(mq0 + 16);
    float4 mA2 = *(const float4*)(mq1);
    float4 mA3 = *(const float4*)(mq1 + 16);
    float4 kB0a,kB0b,kB1a,kB1b, vB0a,vB0b,vB1a,vB1b, mB0,mB1,mB2,mB3;

    KERNEL_QLOAD()

    f32x4 o0[8] = {}, o1[8] = {};
    float l0p = 0.f, l1p = 0.f;

    for (int kt2 = 0; kt2 < NKT / 2; ++kt2) {
        BODY_F32(kA0a,kA0b,kA1a,kA1b, vA0a,vA0b,vA1a,vA1b, mA0,mA1,mA2,mA3,
                 kB0a,kB0b,kB1a,kB1b, vB0a,vB0b,vB1a,vB1b, mB0,mB1,mB2,mB3, 2*kt2)
        BODY_F32(kB0a,kB0b,kB1a,kB1b, vB0a,vB0b,vB1a,vB1b, mB0,mB1,mB2,mB3,
                 kA0a,kA0b,kA1a,kA1b, vA0a,vA0b,vA1a,vA1b, mA0,mA1,mA2,mA3, 2*kt2+1)
    }
    KERNEL_EPILOGUE()
}

extern "C" void kernel_launch(void* const* d_in, const int* in_sizes, int n_in,
                              void* d_out, int out_size, void* d_ws, size_t ws_size,
                              hipStream_t stream) {
    const float* x1   = (const float*)d_in[0];
    const float* x2   = (const float*)d_in[1];
    const float* mask = (const float*)d_in[2];
    float* out = (float*)d_out;
    const size_t need = (size_t)NBH * SK * DD * sizeof(unsigned short);
    if (ws_size >= need) {
        unsigned short* x2b = (unsigned short*)d_ws;
        cvt_x2<<<dim3(2048), dim3(256), 0, stream>>>(x2, x2b, NBH*SK*DD/4);
        fattn_bf16<<<dim3(NBH * (SQ / QBLK)), dim3(256), 0, stream>>>(x1, x2b, mask, out);
    } else {
        fattn_f32<<<dim3(NBH * (SQ / QBLK)), dim3(256), 0, stream>>>(x1, x2, mask, out);
    }
}